// Round 6
// baseline (6380.269 us; speedup 1.0000x reference)
//
#include <hip/hip_runtime.h>

#define LAMF 0.1f
#define LRF  0.01f
#define B1F  0.9f
#define B2F  0.99f
#define EPSF 1e-8f

constexpr int NB = 32;
constexpr int PLANE = 61 * 61;             // 3721
constexpr int USZ = NB * 64 * PLANE;       // u/m/v element count
constexpr int ESZ = NB * 256 * 256;
constexpr int FSZ = 16 * 16 * 64;
// act_pad: [b][c][62 rows][68 slots]; row 61 = permanent zero row,
// slots 0..3 and 65..67 = zero j-pad; interior j at slot j+4.
constexpr int APROW = 68;
constexpr int APPL  = 62 * APROW;          // 4216
constexpr int APSZ  = NB * 64 * APPL;

// ---------------------------------------------------------------------------
// f1[r][c][li][s][k] = filt[4*(3-li)+s][4*(3-k)+r][c]   (16 consecutive = [s][k])
// ---------------------------------------------------------------------------
__global__ __launch_bounds__(256) void permute_filt(const float* __restrict__ filt,
                                                    float* __restrict__ f1) {
    int o = blockIdx.x * 256 + threadIdx.x;
    if (o >= FSZ) return;
    int k  = o & 3;
    int s  = (o >> 2) & 3;
    int ii = (o >> 4) & 3;
    int c  = (o >> 6) & 63;
    int r  = o >> 12;
    int kh = 4 * (3 - ii) + s;
    int kw = 4 * (3 - k) + r;
    f1[o] = filt[(kh * 16 + kw) * 64 + c];
}

// ---------------------------------------------------------------------------
// ek: e = img - conv_transpose(act).  512 threads = 8 waves = (ch x r).
// Wave role: r = phase (x%4) exactly as R3; ch picks a 32-channel half.
// Per-thread state identical to R3 (acc[4][4], ping-pong float4 pairs,
// 76 VGPR) -> fits the 85-VGPR budget of launch_bounds(512,6) = 24 waves/CU.
// ch=1 waves dump partials to LDS ([r][s][lane][4], b128 at 16B lane stride,
// conflict-free); ch=0 waves add and store e.
// ---------------------------------------------------------------------------
#define EK_LOAD(AR, cc)                                        \
  _Pragma("unroll")                                            \
  for (int li = 0; li < 4; ++li) {                             \
    const float* ap = rowp[li] + (cc) * APPL;                  \
    AR[li][0] = *(const float4*)ap;                            \
    AR[li][1] = *(const float4*)(ap + 4);                      \
  }

#define EK_FMA(AR, cc)                                                        \
  {                                                                           \
    const float* fs0 = fbase + (cc) * 64;                                     \
    _Pragma("unroll")                                                         \
    for (int li = 0; li < 4; ++li) {                                          \
      float av[8] = {AR[li][0].x, AR[li][0].y, AR[li][0].z, AR[li][0].w,      \
                     AR[li][1].x, AR[li][1].y, AR[li][1].z, AR[li][1].w};     \
      const float* fs = fs0 + li * 16;                                        \
      _Pragma("unroll")                                                       \
      for (int s = 0; s < 4; ++s) {                                           \
        _Pragma("unroll")                                                     \
        for (int d = 0; d < 4; ++d) {                                         \
          acc[s][d] += av[1 + d + 0] * fs[s * 4 + 0]                          \
                     + av[1 + d + 1] * fs[s * 4 + 1]                          \
                     + av[1 + d + 2] * fs[s * 4 + 2]                          \
                     + av[1 + d + 3] * fs[s * 4 + 3];                         \
        }                                                                     \
      }                                                                       \
    }                                                                         \
  }

__global__ __launch_bounds__(512, 6) void ek(const float* __restrict__ act,
                                             const float* __restrict__ img,
                                             const float* __restrict__ f1,
                                             float* __restrict__ e) {
    __shared__ __align__(16) float red[4 * 4 * 64 * 4];   // 16 KB
    int bid  = blockIdx.x;                    // 512 = 8 XCD * 64
    int n    = (bid & 7) * 64 + (bid >> 3);
    int b    = n >> 4;
    int p0   = (n & 15) * 4;
    int tid  = threadIdx.x;
    int wave = __builtin_amdgcn_readfirstlane(tid >> 6);
    int r    = wave & 3;
    int ch   = wave >> 2;                     // channel half: c in [32ch, 32ch+32)
    int lane = tid & 63;
    int w    = lane >> 4;
    int xh   = lane & 15;

    // per-li row base pointers (row clamped to permanent zero row 61)
    const float* rowp[4];
#pragma unroll
    for (int li = 0; li < 4; ++li) {
        int i   = p0 + w - 3 + li;
        int row = (i >= 0 && i <= 60) ? i : 61;
        rowp[li] = act + (size_t)((b * 64 + ch * 32) * 62 + row) * APROW + 4 * xh;
    }

    float acc[4][4] = {};
    const float* fbase = f1 + r * 4096 + ch * 2048;   // f1[r][c][li][s][k]

    float4 Abuf[4][2], Bbuf[4][2];
    EK_LOAD(Abuf, 0);
    for (int c = 0; c < 32; c += 2) {
        EK_LOAD(Bbuf, c + 1);
        EK_FMA(Abuf, c);
        if (c + 2 < 32) EK_LOAD(Abuf, c + 2);
        EK_FMA(Bbuf, c + 1);
    }

    // cross-wave channel reduction: ch=1 writes, ch=0 adds
    if (ch == 1) {
#pragma unroll
        for (int s = 0; s < 4; ++s)
            *(float4*)&red[((r * 4 + s) * 64 + lane) * 4] =
                make_float4(acc[s][0], acc[s][1], acc[s][2], acc[s][3]);
    }
    __syncthreads();
    if (ch == 0) {
#pragma unroll
        for (int s = 0; s < 4; ++s) {
            float4 t = *(const float4*)&red[((r * 4 + s) * 64 + lane) * 4];
            acc[s][0] += t.x;
            acc[s][1] += t.y;
            acc[s][2] += t.z;
            acc[s][3] += t.w;
        }
#pragma unroll
        for (int s = 0; s < 4; ++s) {
            size_t gi = ((size_t)b * 256 + 4 * (p0 + w) + s) * 256 + 16 * xh + r;
#pragma unroll
            for (int d = 0; d < 4; ++d)
                e[gi + 4 * d] = img[gi + 4 * d] - acc[s][d];
        }
    }
}

// ---------------------------------------------------------------------------
// gk: conv(e,filt) + fused Adam.  1 output row per block (no bounds checks on
// the 16-row e patch), 1952 blocks -> ~24 waves/CU.
// MODE 0: first iter (u=m=v=0 on input).  MODE 1: middle.  MODE 2: last iter,
// writes ONLY the NHWC output relu(u_new - lam).
// ---------------------------------------------------------------------------
template <int MODE>
__global__ __launch_bounds__(256, 6) void gk(float* __restrict__ u,
                                             float* __restrict__ mbuf,
                                             float* __restrict__ vbuf,
                                             float* __restrict__ actp,
                                             float* __restrict__ out,
                                             const float* __restrict__ e,
                                             const float* __restrict__ filt,
                                             float bc1, float bc2) {
    __shared__ __align__(16) float lds[16 * 256];
    int bid = blockIdx.x;                      // 1952 = 8 * 244
    int n   = (bid & 7) * 244 + (bid >> 3);
    int b   = n / 61;
    int i   = n % 61;
    int tid = threadIdx.x;
    int j   = tid & 63;
    int c0  = __builtin_amdgcn_readfirstlane((tid >> 6) * 16);
    int jc  = (j < 61) ? j : 60;

    const float4* e4 = (const float4*)(e + ((size_t)b * 256 + 4 * i) * 256);
    float4* l4 = (float4*)lds;
#pragma unroll
    for (int q = 0; q < 4; ++q) l4[tid + q * 256] = e4[tid + q * 256];
    __syncthreads();

    float acc[16] = {};
    for (int kh = 0; kh < 16; ++kh) {
#pragma unroll
        for (int gw = 0; gw < 4; ++gw) {
            float4 ea = l4[kh * 64 + jc + gw];
            float ev[4] = {ea.x, ea.y, ea.z, ea.w};
#pragma unroll
            for (int t = 0; t < 4; ++t) {
                const float* fc = filt + ((kh * 16 + 4 * gw + t) * 64 + c0);
#pragma unroll
                for (int mm = 0; mm < 16; ++mm)
                    acc[mm] += ev[t] * fc[mm];
            }
        }
    }

    if (j < 61) {
        if (MODE == 2) {
            float ov[16];
#pragma unroll
            for (int mm = 0; mm < 16; ++mm) {
                size_t idx = (size_t)(b * 64 + c0 + mm) * PLANE + i * 61 + j;
                float uu = u[idx];
                float a  = fmaxf(uu - LAMF, 0.f);
                float gg = acc[mm] + a - uu;
                float mv = B1F * mbuf[idx] + (1.f - B1F) * gg;
                float vv = B2F * vbuf[idx] + (1.f - B2F) * gg * gg;
                float un = uu + LRF * (mv / bc1) / (sqrtf(vv / bc2) + EPSF);
                ov[mm] = fmaxf(un - LAMF, 0.f);
            }
            float* op = out + (((size_t)b * 61 + i) * 61 + j) * 64 + c0;
#pragma unroll
            for (int q = 0; q < 4; ++q)
                *(float4*)(op + 4 * q) = make_float4(ov[4 * q], ov[4 * q + 1],
                                                     ov[4 * q + 2], ov[4 * q + 3]);
        } else {
#pragma unroll
            for (int mm = 0; mm < 16; ++mm) {
                size_t idx = (size_t)(b * 64 + c0 + mm) * PLANE + i * 61 + j;
                float uu, a, mprev, vprev;
                if (MODE == 0) {
                    uu = 0.f; a = 0.f; mprev = 0.f; vprev = 0.f;
                } else {
                    uu = u[idx];
                    a  = fmaxf(uu - LAMF, 0.f);
                    mprev = mbuf[idx];
                    vprev = vbuf[idx];
                }
                float gg = acc[mm] + a - uu;
                float mv = B1F * mprev + (1.f - B1F) * gg;
                float vv = B2F * vprev + (1.f - B2F) * gg * gg;
                mbuf[idx] = mv;
                vbuf[idx] = vv;
                float un = uu + LRF * (mv / bc1) / (sqrtf(vv / bc2) + EPSF);
                u[idx] = un;
                actp[(size_t)(b * 64 + c0 + mm) * APPL + (size_t)i * APROW + 4 + j]
                    = fmaxf(un - LAMF, 0.f);
            }
        }
    }
}

// ---------------------------------------------------------------------------
extern "C" void kernel_launch(void* const* d_in, const int* in_sizes, int n_in,
                              void* d_out, int out_size, void* d_ws, size_t ws_size,
                              hipStream_t stream) {
    const float* img  = (const float*)d_in[0];
    const float* filt = (const float*)d_in[1];
    float* out = (float*)d_out;

    float* u    = (float*)d_ws;
    float* mbuf = u + USZ;
    float* vbuf = mbuf + USZ;
    float* e    = vbuf + USZ;
    float* actp = e + ESZ;
    float* f1   = actp + APSZ;

    hipMemsetAsync(actp, 0, (size_t)APSZ * sizeof(float), stream);
    permute_filt<<<FSZ / 256, 256, 0, stream>>>(filt, f1);
    // t = 0: u = 0 -> act = 0 -> e = img exactly
    hipMemcpyAsync(e, img, (size_t)ESZ * sizeof(float), hipMemcpyDeviceToDevice,
                   stream);

    float b1p = B1F, b2p = B2F;
    gk<0><<<1952, 256, 0, stream>>>(u, mbuf, vbuf, actp, out, e, filt,
                                    1.f - b1p, 1.f - b2p);
    for (int t = 1; t < 9; ++t) {
        b1p *= B1F;
        b2p *= B2F;
        ek<<<512, 512, 0, stream>>>(actp, img, f1, e);
        gk<1><<<1952, 256, 0, stream>>>(u, mbuf, vbuf, actp, out, e, filt,
                                        1.f - b1p, 1.f - b2p);
    }
    b1p *= B1F;
    b2p *= B2F;
    ek<<<512, 512, 0, stream>>>(actp, img, f1, e);
    gk<2><<<1952, 256, 0, stream>>>(u, mbuf, vbuf, actp, out, e, filt,
                                    1.f - b1p, 1.f - b2p);
}

// Round 7
// 1684.311 us; speedup vs baseline: 3.7881x; 3.7881x over previous
//
#include <hip/hip_runtime.h>

#define LAMF 0.1f
#define LRF  0.01f
#define B1F  0.9f
#define B2F  0.99f
#define EPSF 1e-8f

constexpr int NB = 32;
constexpr int PLANE = 61 * 61;             // 3721
constexpr int USZ = NB * 64 * PLANE;       // u/m/v element count
constexpr int ESZ = NB * 256 * 256;
constexpr int FSZ = 16 * 16 * 64;
// act_pad: [b][c][62 rows][68 slots]; row 61 = permanent zero row,
// slots 0..3 and 65..67 = zero j-pad; interior j at slot j+4.
constexpr int APROW = 68;
constexpr int APPL  = 62 * APROW;          // 4216
constexpr int APSZ  = NB * 64 * APPL;

// NOTE (measured R5/R6): on this toolchain __launch_bounds__' 2nd arg acts as
// min BLOCKS per CU; VGPR cap = 131072 / (block_threads * arg2).
//   (512,4) -> 64 VGPR (R5, mild spill) ; (512,6) -> 40 VGPR (R6, 2.1 GB spill
//   traffic, 4x regression) ; (512,3) -> 85 VGPR cap (this round, fits ~76).

// ---------------------------------------------------------------------------
// f1[r][c][li][s][k] = filt[4*(3-li)+s][4*(3-k)+r][c]   (16 consecutive = [s][k])
// ---------------------------------------------------------------------------
__global__ __launch_bounds__(256) void permute_filt(const float* __restrict__ filt,
                                                    float* __restrict__ f1) {
    int o = blockIdx.x * 256 + threadIdx.x;
    if (o >= FSZ) return;
    int k  = o & 3;
    int s  = (o >> 2) & 3;
    int ii = (o >> 4) & 3;
    int c  = (o >> 6) & 63;
    int r  = o >> 12;
    int kh = 4 * (3 - ii) + s;
    int kw = 4 * (3 - k) + r;
    f1[o] = filt[(kh * 16 + kw) * 64 + c];
}

// ---------------------------------------------------------------------------
// ek: e = img - conv_transpose(act).  512 threads = 8 waves = (ch x r).
// Wave role: r = phase (x%4) exactly as R3; ch picks a 32-channel half.
// Per-thread state identical to R3 (acc[4][4], ping-pong float4 pairs,
// ~76 VGPR) -> fits the 85-VGPR cap of (512,3).
// ch=1 waves dump partials to LDS ([r][s][lane][4], b128 at 16B lane stride,
// conflict-free); ch=0 waves add and store e.
// ---------------------------------------------------------------------------
#define EK_LOAD(AR, cc)                                        \
  _Pragma("unroll")                                            \
  for (int li = 0; li < 4; ++li) {                             \
    const float* ap = rowp[li] + (cc) * APPL;                  \
    AR[li][0] = *(const float4*)ap;                            \
    AR[li][1] = *(const float4*)(ap + 4);                      \
  }

#define EK_FMA(AR, cc)                                                        \
  {                                                                           \
    const float* fs0 = fbase + (cc) * 64;                                     \
    _Pragma("unroll")                                                         \
    for (int li = 0; li < 4; ++li) {                                          \
      float av[8] = {AR[li][0].x, AR[li][0].y, AR[li][0].z, AR[li][0].w,      \
                     AR[li][1].x, AR[li][1].y, AR[li][1].z, AR[li][1].w};     \
      const float* fs = fs0 + li * 16;                                        \
      _Pragma("unroll")                                                       \
      for (int s = 0; s < 4; ++s) {                                           \
        _Pragma("unroll")                                                     \
        for (int d = 0; d < 4; ++d) {                                         \
          acc[s][d] += av[1 + d + 0] * fs[s * 4 + 0]                          \
                     + av[1 + d + 1] * fs[s * 4 + 1]                          \
                     + av[1 + d + 2] * fs[s * 4 + 2]                          \
                     + av[1 + d + 3] * fs[s * 4 + 3];                         \
        }                                                                     \
      }                                                                       \
    }                                                                         \
  }

__global__ __launch_bounds__(512, 3) void ek(const float* __restrict__ act,
                                             const float* __restrict__ img,
                                             const float* __restrict__ f1,
                                             float* __restrict__ e) {
    __shared__ __align__(16) float red[4 * 4 * 64 * 4];   // 16 KB
    int bid  = blockIdx.x;                    // 512 = 8 XCD * 64
    int n    = (bid & 7) * 64 + (bid >> 3);
    int b    = n >> 4;
    int p0   = (n & 15) * 4;
    int tid  = threadIdx.x;
    int wave = __builtin_amdgcn_readfirstlane(tid >> 6);
    int r    = wave & 3;
    int ch   = wave >> 2;                     // channel half: c in [32ch, 32ch+32)
    int lane = tid & 63;
    int w    = lane >> 4;
    int xh   = lane & 15;

    // per-li row base pointers (row clamped to permanent zero row 61)
    const float* rowp[4];
#pragma unroll
    for (int li = 0; li < 4; ++li) {
        int i   = p0 + w - 3 + li;
        int row = (i >= 0 && i <= 60) ? i : 61;
        rowp[li] = act + (size_t)((b * 64 + ch * 32) * 62 + row) * APROW + 4 * xh;
    }

    float acc[4][4] = {};
    const float* fbase = f1 + r * 4096 + ch * 2048;   // f1[r][c][li][s][k]

    float4 Abuf[4][2], Bbuf[4][2];
    EK_LOAD(Abuf, 0);
    for (int c = 0; c < 32; c += 2) {
        EK_LOAD(Bbuf, c + 1);
        EK_FMA(Abuf, c);
        if (c + 2 < 32) EK_LOAD(Abuf, c + 2);
        EK_FMA(Bbuf, c + 1);
    }

    // cross-wave channel reduction: ch=1 writes, ch=0 adds
    if (ch == 1) {
#pragma unroll
        for (int s = 0; s < 4; ++s)
            *(float4*)&red[((r * 4 + s) * 64 + lane) * 4] =
                make_float4(acc[s][0], acc[s][1], acc[s][2], acc[s][3]);
    }
    __syncthreads();
    if (ch == 0) {
#pragma unroll
        for (int s = 0; s < 4; ++s) {
            float4 t = *(const float4*)&red[((r * 4 + s) * 64 + lane) * 4];
            acc[s][0] += t.x;
            acc[s][1] += t.y;
            acc[s][2] += t.z;
            acc[s][3] += t.w;
        }
#pragma unroll
        for (int s = 0; s < 4; ++s) {
            size_t gi = ((size_t)b * 256 + 4 * (p0 + w) + s) * 256 + 16 * xh + r;
#pragma unroll
            for (int d = 0; d < 4; ++d)
                e[gi + 4 * d] = img[gi + 4 * d] - acc[s][d];
        }
    }
}

// ---------------------------------------------------------------------------
// gk: conv(e,filt) + fused Adam.  1 output row per block (no bounds checks on
// the 16-row e patch), 1952 blocks.
// MODE 0: first iter (u=m=v=0 on input).  MODE 1: middle.  MODE 2: last iter,
// writes ONLY the NHWC output relu(u_new - lam).
// ---------------------------------------------------------------------------
template <int MODE>
__global__ __launch_bounds__(256, 6) void gk(float* __restrict__ u,
                                             float* __restrict__ mbuf,
                                             float* __restrict__ vbuf,
                                             float* __restrict__ actp,
                                             float* __restrict__ out,
                                             const float* __restrict__ e,
                                             const float* __restrict__ filt,
                                             float bc1, float bc2) {
    __shared__ __align__(16) float lds[16 * 256];
    int bid = blockIdx.x;                      // 1952 = 8 * 244
    int n   = (bid & 7) * 244 + (bid >> 3);
    int b   = n / 61;
    int i   = n % 61;
    int tid = threadIdx.x;
    int j   = tid & 63;
    int c0  = __builtin_amdgcn_readfirstlane((tid >> 6) * 16);
    int jc  = (j < 61) ? j : 60;

    const float4* e4 = (const float4*)(e + ((size_t)b * 256 + 4 * i) * 256);
    float4* l4 = (float4*)lds;
#pragma unroll
    for (int q = 0; q < 4; ++q) l4[tid + q * 256] = e4[tid + q * 256];
    __syncthreads();

    float acc[16] = {};
    for (int kh = 0; kh < 16; ++kh) {
#pragma unroll
        for (int gw = 0; gw < 4; ++gw) {
            float4 ea = l4[kh * 64 + jc + gw];
            float ev[4] = {ea.x, ea.y, ea.z, ea.w};
#pragma unroll
            for (int t = 0; t < 4; ++t) {
                const float* fc = filt + ((kh * 16 + 4 * gw + t) * 64 + c0);
#pragma unroll
                for (int mm = 0; mm < 16; ++mm)
                    acc[mm] += ev[t] * fc[mm];
            }
        }
    }

    if (j < 61) {
        if (MODE == 2) {
            float ov[16];
#pragma unroll
            for (int mm = 0; mm < 16; ++mm) {
                size_t idx = (size_t)(b * 64 + c0 + mm) * PLANE + i * 61 + j;
                float uu = u[idx];
                float a  = fmaxf(uu - LAMF, 0.f);
                float gg = acc[mm] + a - uu;
                float mv = B1F * mbuf[idx] + (1.f - B1F) * gg;
                float vv = B2F * vbuf[idx] + (1.f - B2F) * gg * gg;
                float un = uu + LRF * (mv / bc1) / (sqrtf(vv / bc2) + EPSF);
                ov[mm] = fmaxf(un - LAMF, 0.f);
            }
            float* op = out + (((size_t)b * 61 + i) * 61 + j) * 64 + c0;
#pragma unroll
            for (int q = 0; q < 4; ++q)
                *(float4*)(op + 4 * q) = make_float4(ov[4 * q], ov[4 * q + 1],
                                                     ov[4 * q + 2], ov[4 * q + 3]);
        } else {
#pragma unroll
            for (int mm = 0; mm < 16; ++mm) {
                size_t idx = (size_t)(b * 64 + c0 + mm) * PLANE + i * 61 + j;
                float uu, a, mprev, vprev;
                if (MODE == 0) {
                    uu = 0.f; a = 0.f; mprev = 0.f; vprev = 0.f;
                } else {
                    uu = u[idx];
                    a  = fmaxf(uu - LAMF, 0.f);
                    mprev = mbuf[idx];
                    vprev = vbuf[idx];
                }
                float gg = acc[mm] + a - uu;
                float mv = B1F * mprev + (1.f - B1F) * gg;
                float vv = B2F * vprev + (1.f - B2F) * gg * gg;
                mbuf[idx] = mv;
                vbuf[idx] = vv;
                float un = uu + LRF * (mv / bc1) / (sqrtf(vv / bc2) + EPSF);
                u[idx] = un;
                actp[(size_t)(b * 64 + c0 + mm) * APPL + (size_t)i * APROW + 4 + j]
                    = fmaxf(un - LAMF, 0.f);
            }
        }
    }
}

// ---------------------------------------------------------------------------
extern "C" void kernel_launch(void* const* d_in, const int* in_sizes, int n_in,
                              void* d_out, int out_size, void* d_ws, size_t ws_size,
                              hipStream_t stream) {
    const float* img  = (const float*)d_in[0];
    const float* filt = (const float*)d_in[1];
    float* out = (float*)d_out;

    float* u    = (float*)d_ws;
    float* mbuf = u + USZ;
    float* vbuf = mbuf + USZ;
    float* e    = vbuf + USZ;
    float* actp = e + ESZ;
    float* f1   = actp + APSZ;

    hipMemsetAsync(actp, 0, (size_t)APSZ * sizeof(float), stream);
    permute_filt<<<FSZ / 256, 256, 0, stream>>>(filt, f1);
    // t = 0: u = 0 -> act = 0 -> e = img exactly
    hipMemcpyAsync(e, img, (size_t)ESZ * sizeof(float), hipMemcpyDeviceToDevice,
                   stream);

    float b1p = B1F, b2p = B2F;
    gk<0><<<1952, 256, 0, stream>>>(u, mbuf, vbuf, actp, out, e, filt,
                                    1.f - b1p, 1.f - b2p);
    for (int t = 1; t < 9; ++t) {
        b1p *= B1F;
        b2p *= B2F;
        ek<<<512, 512, 0, stream>>>(actp, img, f1, e);
        gk<1><<<1952, 256, 0, stream>>>(u, mbuf, vbuf, actp, out, e, filt,
                                        1.f - b1p, 1.f - b2p);
    }
    b1p *= B1F;
    b2p *= B2F;
    ek<<<512, 512, 0, stream>>>(actp, img, f1, e);
    gk<2><<<1952, 256, 0, stream>>>(u, mbuf, vbuf, actp, out, e, filt,
                                    1.f - b1p, 1.f - b2p);
}

// Round 8
// 703.371 us; speedup vs baseline: 9.0710x; 2.3946x over previous
//
#include <hip/hip_runtime.h>

#define LAMF 0.1f
#define LRF  0.01f
#define B1F  0.9f
#define B2F  0.99f
#define EPSF 1e-8f

constexpr int NB = 32;
constexpr int PLANE = 61 * 61;            // 3721
constexpr int USZ = NB * 64 * PLANE;      // u/m/v f32 elements
constexpr int ESZ = NB * 256 * 256;       // e f16 elements
constexpr int ACSZ = NB * 62 * 68 * 64;   // act NHWC-padded f16 elements

// NOTE (measured R5/R6): __launch_bounds__ 2nd arg acts as min BLOCKS/CU here;
// VGPR cap = 131072/(threads*arg2). (512,6) gave 40 VGPR and a 4x spill
// regression. -> No 2nd arg anywhere in this file.

typedef _Float16 f16;
typedef __attribute__((ext_vector_type(8))) _Float16 f16x8;
typedef f16x8 f16x8u __attribute__((aligned(8)));    // 8B-aligned 16B load
typedef __attribute__((ext_vector_type(4))) _Float16 f16x4;
typedef __attribute__((ext_vector_type(4))) float f32x4;
typedef f32x4 f32x4u __attribute__((aligned(4)));    // 4B-aligned 16B ld/st

// ---------------------------------------------------------------------------
// prep: filter into exact MFMA B-fragment order (f16).
//  F2f (ek):  [ks 0..31][lane][e]  k = tap*64+c ; tap=(ii,kk), n=(s,r)=lane&15
//  Bf  (gk):  [ks 0..7][nt 0..3][lane][e]  k = kh*16+kw ; n = c
// ---------------------------------------------------------------------------
__global__ __launch_bounds__(256) void prep(const float* __restrict__ filt,
                                            f16* __restrict__ F2f,
                                            f16* __restrict__ Bf) {
    int o = blockIdx.x * 256 + threadIdx.x;       // 32768 threads
    if (o < 16384) {
        int e = o & 7, lane = (o >> 3) & 63, ks = o >> 9;
        int nn = lane & 15, kg = lane >> 4;
        int tap = ks >> 1, ii = tap >> 2, kk = tap & 3;
        int c = (ks & 1) * 32 + kg * 8 + e;
        int s = nn >> 2, r = nn & 3;
        F2f[o] = (f16)filt[((4 * (3 - ii) + s) * 16 + (4 * (3 - kk) + r)) * 64 + c];
    } else {
        int o2 = o - 16384;
        int e = o2 & 7, lane = (o2 >> 3) & 63;
        int nt = (o2 >> 9) & 3, ks = o2 >> 11;
        int k = ks * 32 + (lane >> 4) * 8 + e;
        int c = nt * 16 + (lane & 15);
        Bf[o2] = (f16)filt[k * 64 + c];
    }
}

// eh = (f16)img   (t=0: act=0 -> e = img)
__global__ __launch_bounds__(256) void cvt(const float* __restrict__ img,
                                           f16* __restrict__ eh) {
    int o = blockIdx.x * 256 + threadIdx.x;       // ESZ/4 threads
    f32x4 v = ((const f32x4*)img)[o];
    f16x4 h = {(f16)v[0], (f16)v[1], (f16)v[2], (f16)v[3]};
    *(f16x4*)(eh + (size_t)o * 4) = h;
}

// ---------------------------------------------------------------------------
// ek (MFMA): e = img - conv_T(act).  GEMM M=(b,p,q) N=16 phases K=1024.
// act NHWC-padded f16: [b][row 0..61][slot 0..67][c 0..63]; row61 + edge
// slots stay zero.  Block 256 thr = 4 waves = (2 p) x (2 q-halves); each wave
// does 2 M-tiles of 16 q.  A-frag: one 16B load; B-frag: ds_read from staged
// F2f.  mfma(A,B): lane&15 of A = q (out row), of B = n (out col).
// ---------------------------------------------------------------------------
__global__ __launch_bounds__(256) void ek(const f16* __restrict__ actc,
                                          const float* __restrict__ img,
                                          const f16* __restrict__ F2f,
                                          f16* __restrict__ eh) {
    __shared__ f16 BS[32 * 64 * 8];               // 32 KB
    int tid = threadIdx.x;
    {
        const f32x4* s = (const f32x4*)F2f;
        f32x4* d = (f32x4*)BS;
        for (int idx = tid; idx < 2048; idx += 256) d[idx] = s[idx];
    }
    __syncthreads();

    int bid = blockIdx.x;                         // 1024 = 8 XCD * 128
    int n   = (bid & 7) * 128 + (bid >> 3);
    int b   = n >> 5;
    int pg  = n & 31;
    int wave = __builtin_amdgcn_readfirstlane(tid >> 6);
    int lane = tid & 63;
    int p  = pg * 2 + (wave >> 1);
    int qh = wave & 1;
    int kg = lane >> 4;
    int ml = lane & 15;

    const f16* rowp[4];
#pragma unroll
    for (int ii = 0; ii < 4; ++ii) {
        int row = p - 3 + ii;
        if (row < 0 || row > 60) row = 61;        // permanent zero row
        rowp[ii] = actc + (size_t)(b * 62 + row) * 68 * 64;
    }
    int q0 = qh * 32 + ml;

    f32x4 acc0 = {0.f, 0.f, 0.f, 0.f};
    f32x4 acc1 = {0.f, 0.f, 0.f, 0.f};
#pragma unroll
    for (int ks = 0; ks < 32; ++ks) {
        int tap = ks >> 1;
        int ii  = tap >> 2;
        int kk  = tap & 3;
        int c0  = (ks & 1) * 32 + kg * 8;
        const f16* base = rowp[ii] + (kk + 1) * 64 + c0;    // slot = q+1+kk
        f16x8 Bfr = *(const f16x8*)(BS + (ks * 64 + lane) * 8);
        f16x8 A0  = *(const f16x8u*)(base + q0 * 64);
        f16x8 A1  = *(const f16x8u*)(base + (q0 + 16) * 64);
        acc0 = __builtin_amdgcn_mfma_f32_16x16x32_f16(A0, Bfr, acc0, 0, 0, 0);
        acc1 = __builtin_amdgcn_mfma_f32_16x16x32_f16(A1, Bfr, acc1, 0, 0, 0);
    }

    // D: col = lane&15 = n=(s,r); row = (lane>>4)*4 + reg = q offset
    int s_ = (lane & 15) >> 2;
    int r_ = lane & 3;
    int qr = (lane >> 4) * 4;
    size_t rowbase = ((size_t)b * 256 + 4 * p + s_) * 256 + r_;
#pragma unroll
    for (int t = 0; t < 2; ++t) {
        f32x4 a = t ? acc1 : acc0;
#pragma unroll
        for (int rg = 0; rg < 4; ++rg) {
            int qq = qh * 32 + t * 16 + qr + rg;
            size_t gi = rowbase + (size_t)4 * qq;
            eh[gi] = (f16)(img[gi] - a[rg]);
        }
    }
}

// ---------------------------------------------------------------------------
// gk (MFMA): conv(e,filt) + fused fp32 Adam.  GEMM M=(b,i,j) N=64c K=256.
// Block = (b,i), wave = j-tile.  MODE 0: first iter (no state reads).
// MODE 1: middle.  MODE 2: last iter -> writes ONLY NHWC out.
// ---------------------------------------------------------------------------
template <int MODE>
__global__ __launch_bounds__(256) void gk(float* __restrict__ u,
                                          float* __restrict__ mb,
                                          float* __restrict__ vb,
                                          f16* __restrict__ actc,
                                          float* __restrict__ out,
                                          const f16* __restrict__ eh,
                                          const f16* __restrict__ Bf,
                                          float rbc1, float rbc2) {
    __shared__ f16 BS[8 * 4 * 64 * 8];            // 16 KB
    int tid = threadIdx.x;
    {
        const f32x4* s = (const f32x4*)Bf;
        f32x4* d = (f32x4*)BS;
        for (int idx = tid; idx < 1024; idx += 256) d[idx] = s[idx];
    }
    __syncthreads();

    int bid = blockIdx.x;                         // 1952 = 8 * 244
    int n   = (bid & 7) * 244 + (bid >> 3);
    int b   = n / 61;
    int i   = n % 61;
    int jt  = __builtin_amdgcn_readfirstlane(tid >> 6);
    int lane = tid & 63;
    int kg  = lane >> 4;
    int ml  = lane & 15;

    // A: lane&15 = j, k = (lane>>4)*8+e ; k=(kh,kw): kh=2ks+(kg>>1), kw=(kg&1)*8+e
    const f16* ebase = eh + ((size_t)b * 256 + 4 * i) * 256
                     + 4 * (jt * 16 + ml) + (kg & 1) * 8;
    int khb = kg >> 1;

    f32x4 acc[4] = {{0.f,0.f,0.f,0.f}, {0.f,0.f,0.f,0.f},
                    {0.f,0.f,0.f,0.f}, {0.f,0.f,0.f,0.f}};
#pragma unroll
    for (int ks = 0; ks < 8; ++ks) {
        f16x8 A = *(const f16x8u*)(ebase + (2 * ks + khb) * 256);
#pragma unroll
        for (int nt = 0; nt < 4; ++nt) {
            f16x8 B = *(const f16x8*)(BS + ((ks * 4 + nt) * 64 + lane) * 8);
            acc[nt] = __builtin_amdgcn_mfma_f32_16x16x32_f16(A, B, acc[nt], 0, 0, 0);
        }
    }

    // D: col = lane&15 = c offset; row = (lane>>4)*4+reg = j offset
    int j0 = jt * 16 + (lane >> 4) * 4;           // <= 60; j0+3 may reach 63
    bool full = (j0 <= 56);
#pragma unroll
    for (int nt = 0; nt < 4; ++nt) {
        int cc = nt * 16 + (lane & 15);
        size_t sbase = (size_t)(b * 64 + cc) * PLANE + (size_t)i * 61 + j0;
        float un[4];
        if (MODE == 0) {
#pragma unroll
            for (int rg = 0; rg < 4; ++rg) {
                float g  = acc[nt][rg];
                float m2 = (1.f - B1F) * g;
                float v2 = (1.f - B2F) * g * g;
                un[rg] = LRF * (m2 * rbc1) / (sqrtf(v2 * rbc2) + EPSF);
                acc[nt][rg] = m2;                 // reuse acc as m2 store vec
                // stash v2 via recompute below
            }
            f32x4 m4 = {acc[nt][0], acc[nt][1], acc[nt][2], acc[nt][3]};
            f32x4 u4 = {un[0], un[1], un[2], un[3]};
            f32x4 v4;
#pragma unroll
            for (int rg = 0; rg < 4; ++rg) {
                float g = m4[rg] / (1.f - B1F);
                v4[rg] = (1.f - B2F) * g * g;
            }
            if (full) {
                *(f32x4u*)(u + sbase)  = u4;
                *(f32x4u*)(mb + sbase) = m4;
                *(f32x4u*)(vb + sbase) = v4;
            } else {
                u[sbase] = u4[0]; mb[sbase] = m4[0]; vb[sbase] = v4[0];
            }
            f16* ab = actc + ((size_t)(b * 62 + i) * 68 + (j0 + 4)) * 64 + cc;
#pragma unroll
            for (int rg = 0; rg < 4; ++rg)
                if (j0 + rg <= 60) ab[rg * 64] = (f16)fmaxf(un[rg] - LAMF, 0.f);
        } else {
            f32x4 uu = *(const f32x4u*)(u + sbase);
            f32x4 mm = *(const f32x4u*)(mb + sbase);
            f32x4 vv = *(const f32x4u*)(vb + sbase);
#pragma unroll
            for (int rg = 0; rg < 4; ++rg) {
                float a  = fmaxf(uu[rg] - LAMF, 0.f);
                float g  = acc[nt][rg] + a - uu[rg];
                float m2 = B1F * mm[rg] + (1.f - B1F) * g;
                float v2 = B2F * vv[rg] + (1.f - B2F) * g * g;
                mm[rg] = m2;
                vv[rg] = v2;
                un[rg] = uu[rg] + LRF * (m2 * rbc1) / (sqrtf(v2 * rbc2) + EPSF);
            }
            if (MODE == 1) {
                f32x4 u4 = {un[0], un[1], un[2], un[3]};
                if (full) {
                    *(f32x4u*)(u + sbase)  = u4;
                    *(f32x4u*)(mb + sbase) = mm;
                    *(f32x4u*)(vb + sbase) = vv;
                } else {
                    u[sbase] = un[0]; mb[sbase] = mm[0]; vb[sbase] = vv[0];
                }
                f16* ab = actc + ((size_t)(b * 62 + i) * 68 + (j0 + 4)) * 64 + cc;
#pragma unroll
                for (int rg = 0; rg < 4; ++rg)
                    if (j0 + rg <= 60) ab[rg * 64] = (f16)fmaxf(un[rg] - LAMF, 0.f);
            } else {                              // MODE 2: output only
                float* ob = out + (((size_t)b * 61 + i) * 61 + j0) * 64 + cc;
#pragma unroll
                for (int rg = 0; rg < 4; ++rg)
                    if (j0 + rg <= 60) ob[rg * 64] = fmaxf(un[rg] - LAMF, 0.f);
            }
        }
    }
}

// ---------------------------------------------------------------------------
extern "C" void kernel_launch(void* const* d_in, const int* in_sizes, int n_in,
                              void* d_out, int out_size, void* d_ws, size_t ws_size,
                              hipStream_t stream) {
    const float* img  = (const float*)d_in[0];
    const float* filt = (const float*)d_in[1];
    float* out = (float*)d_out;

    float* u  = (float*)d_ws;
    float* mb = u + USZ;
    float* vb = mb + USZ;
    f16* eh   = (f16*)(vb + USZ);     // eh before actc: tail OOB reads land in actc
    f16* actc = eh + ESZ;
    f16* F2f  = actc + ACSZ;
    f16* Bf   = F2f + 16384;

    hipMemsetAsync(actc, 0, (size_t)ACSZ * sizeof(f16), stream);
    prep<<<128, 256, 0, stream>>>(filt, F2f, Bf);
    cvt<<<ESZ / 1024, 256, 0, stream>>>(img, eh);

    float b1p = B1F, b2p = B2F;
    gk<0><<<1952, 256, 0, stream>>>(u, mb, vb, actc, out, eh, Bf,
                                    1.f / (1.f - b1p), 1.f / (1.f - b2p));
    for (int t = 1; t < 9; ++t) {
        b1p *= B1F;
        b2p *= B2F;
        ek<<<1024, 256, 0, stream>>>(actc, img, F2f, eh);
        gk<1><<<1952, 256, 0, stream>>>(u, mb, vb, actc, out, eh, Bf,
                                        1.f / (1.f - b1p), 1.f / (1.f - b2p));
    }
    b1p *= B1F;
    b2p *= B2F;
    ek<<<1024, 256, 0, stream>>>(actc, img, F2f, eh);
    gk<2><<<1952, 256, 0, stream>>>(u, mb, vb, actc, out, eh, Bf,
                                    1.f / (1.f - b1p), 1.f / (1.f - b2p));
}

// Round 9
// 629.203 us; speedup vs baseline: 10.1402x; 1.1179x over previous
//
#include <hip/hip_runtime.h>

#define LAMF 0.1f
#define LRF  0.01f
#define B1F  0.9f
#define B2F  0.99f
#define EPSF 1e-8f

constexpr int NB = 32;
constexpr int PLANE = 61 * 61;            // 3721
constexpr int USZ = NB * 64 * PLANE;      // u f32 elements (m,v packed f16 pairs)
constexpr int ESZ = NB * 256 * 256;       // e f16 elements
constexpr int ACSZ = NB * 62 * 68 * 64;   // act NHWC-padded f16 elements

// NOTE (measured R5/R6): __launch_bounds__ 2nd arg acts as min BLOCKS/CU here;
// VGPR cap = 131072/(threads*arg2). (512,6) gave 40 VGPR and a 4x spill
// regression. -> No 2nd arg anywhere in this file.

typedef _Float16 f16;
typedef __attribute__((ext_vector_type(8))) _Float16 f16x8;
typedef f16x8 f16x8u __attribute__((aligned(8)));    // 8B-aligned 16B load
typedef f16x8 f16x8a __attribute__((aligned(4)));    // 4B-aligned 16B load (mv)
typedef __attribute__((ext_vector_type(4))) _Float16 f16x4;
typedef __attribute__((ext_vector_type(4))) float f32x4;
typedef f32x4 f32x4u __attribute__((aligned(4)));    // 4B-aligned 16B ld/st

// ---------------------------------------------------------------------------
// prep: filter into exact MFMA B-fragment order (f16).
//  F2f (ek):  [ks 0..31][lane][e]  k = tap*64+c ; tap=(ii,kk), n=(s,r)=lane&15
//  Bf  (gk):  [ks 0..7][nt 0..3][lane][e]  k = kh*16+kw ; n = c
// ---------------------------------------------------------------------------
__global__ __launch_bounds__(256) void prep(const float* __restrict__ filt,
                                            f16* __restrict__ F2f,
                                            f16* __restrict__ Bf) {
    int o = blockIdx.x * 256 + threadIdx.x;       // 32768 threads
    if (o < 16384) {
        int e = o & 7, lane = (o >> 3) & 63, ks = o >> 9;
        int nn = lane & 15, kg = lane >> 4;
        int tap = ks >> 1, ii = tap >> 2, kk = tap & 3;
        int c = (ks & 1) * 32 + kg * 8 + e;
        int s = nn >> 2, r = nn & 3;
        F2f[o] = (f16)filt[((4 * (3 - ii) + s) * 16 + (4 * (3 - kk) + r)) * 64 + c];
    } else {
        int o2 = o - 16384;
        int e = o2 & 7, lane = (o2 >> 3) & 63;
        int nt = (o2 >> 9) & 3, ks = o2 >> 11;
        int k = ks * 32 + (lane >> 4) * 8 + e;
        int c = nt * 16 + (lane & 15);
        Bf[o2] = (f16)filt[k * 64 + c];
    }
}

// eh = (f16)img   (t=0: act=0 -> e = img)
__global__ __launch_bounds__(256) void cvt(const float* __restrict__ img,
                                           f16* __restrict__ eh) {
    int o = blockIdx.x * 256 + threadIdx.x;       // ESZ/4 threads
    f32x4 v = ((const f32x4*)img)[o];
    f16x4 h = {(f16)v[0], (f16)v[1], (f16)v[2], (f16)v[3]};
    *(f16x4*)(eh + (size_t)o * 4) = h;
}

// ---------------------------------------------------------------------------
// ek (MFMA): e = img - conv_T(act).  GEMM M=(b,p,q) N=16 phases K=1024.
// act NHWC-padded f16: [b][row 0..61][slot 0..67][c 0..63]; row61 + edge
// slots stay zero.  Block 256 thr = 4 waves = (2 p) x (2 q-halves); each wave
// does 2 M-tiles of 16 q.  A-frag: one 16B load; B-frag: ds_read from staged
// F2f.  mfma(A,B): lane&15 of A = q (out row), of B = n (out col).
// ---------------------------------------------------------------------------
__global__ __launch_bounds__(256) void ek(const f16* __restrict__ actc,
                                          const float* __restrict__ img,
                                          const f16* __restrict__ F2f,
                                          f16* __restrict__ eh) {
    __shared__ f16 BS[32 * 64 * 8];               // 32 KB
    int tid = threadIdx.x;
    {
        const f32x4* s = (const f32x4*)F2f;
        f32x4* d = (f32x4*)BS;
        for (int idx = tid; idx < 2048; idx += 256) d[idx] = s[idx];
    }
    __syncthreads();

    int bid = blockIdx.x;                         // 1024 = 8 XCD * 128
    int n   = (bid & 7) * 128 + (bid >> 3);
    int b   = n >> 5;
    int pg  = n & 31;
    int wave = __builtin_amdgcn_readfirstlane(tid >> 6);
    int lane = tid & 63;
    int p  = pg * 2 + (wave >> 1);
    int qh = wave & 1;
    int kg = lane >> 4;
    int ml = lane & 15;

    const f16* rowp[4];
#pragma unroll
    for (int ii = 0; ii < 4; ++ii) {
        int row = p - 3 + ii;
        if (row < 0 || row > 60) row = 61;        // permanent zero row
        rowp[ii] = actc + (size_t)(b * 62 + row) * 68 * 64;
    }
    int q0 = qh * 32 + ml;

    f32x4 acc0 = {0.f, 0.f, 0.f, 0.f};
    f32x4 acc1 = {0.f, 0.f, 0.f, 0.f};
#pragma unroll
    for (int ks = 0; ks < 32; ++ks) {
        int tap = ks >> 1;
        int ii  = tap >> 2;
        int kk  = tap & 3;
        int c0  = (ks & 1) * 32 + kg * 8;
        const f16* base = rowp[ii] + (kk + 1) * 64 + c0;    // slot = q+1+kk
        f16x8 Bfr = *(const f16x8*)(BS + (ks * 64 + lane) * 8);
        f16x8 A0  = *(const f16x8u*)(base + q0 * 64);
        f16x8 A1  = *(const f16x8u*)(base + (q0 + 16) * 64);
        acc0 = __builtin_amdgcn_mfma_f32_16x16x32_f16(A0, Bfr, acc0, 0, 0, 0);
        acc1 = __builtin_amdgcn_mfma_f32_16x16x32_f16(A1, Bfr, acc1, 0, 0, 0);
    }

    // D: col = lane&15 = n=(s,r); row = (lane>>4)*4 + reg = q offset
    int s_ = (lane & 15) >> 2;
    int r_ = lane & 3;
    int qr = (lane >> 4) * 4;
    size_t rowbase = ((size_t)b * 256 + 4 * p + s_) * 256 + r_;
#pragma unroll
    for (int t = 0; t < 2; ++t) {
        f32x4 a = t ? acc1 : acc0;
#pragma unroll
        for (int rg = 0; rg < 4; ++rg) {
            int qq = qh * 32 + t * 16 + qr + rg;
            size_t gi = rowbase + (size_t)4 * qq;
            eh[gi] = (f16)(img[gi] - a[rg]);
        }
    }
}

// ---------------------------------------------------------------------------
// gk (MFMA): conv(e,filt) + fused Adam.  GEMM M=(b,i,j) N=64c K=256.
// u fp32; m,v interleaved f16 pairs in mv (one 16B f16x8 = 4 (m,v) pairs).
// Block = (b,i), wave = j-tile.  MODE 0: first iter (no state reads).
// MODE 1: middle.  MODE 2: last iter -> writes ONLY NHWC out.
// ---------------------------------------------------------------------------
template <int MODE>
__global__ __launch_bounds__(256) void gk(float* __restrict__ u,
                                          f16* __restrict__ mv,
                                          f16* __restrict__ actc,
                                          float* __restrict__ out,
                                          const f16* __restrict__ eh,
                                          const f16* __restrict__ Bf,
                                          float rbc1, float rbc2) {
    __shared__ f16 BS[8 * 4 * 64 * 8];            // 16 KB
    int tid = threadIdx.x;
    {
        const f32x4* s = (const f32x4*)Bf;
        f32x4* d = (f32x4*)BS;
        for (int idx = tid; idx < 1024; idx += 256) d[idx] = s[idx];
    }
    __syncthreads();

    int bid = blockIdx.x;                         // 1952 = 8 * 244
    int n   = (bid & 7) * 244 + (bid >> 3);
    int b   = n / 61;
    int i   = n % 61;
    int jt  = __builtin_amdgcn_readfirstlane(tid >> 6);
    int lane = tid & 63;
    int kg  = lane >> 4;
    int ml  = lane & 15;

    // A: lane&15 = j, k = (lane>>4)*8+e ; k=(kh,kw): kh=2ks+(kg>>1), kw=(kg&1)*8+e
    const f16* ebase = eh + ((size_t)b * 256 + 4 * i) * 256
                     + 4 * (jt * 16 + ml) + (kg & 1) * 8;
    int khb = kg >> 1;

    f32x4 acc[4] = {{0.f,0.f,0.f,0.f}, {0.f,0.f,0.f,0.f},
                    {0.f,0.f,0.f,0.f}, {0.f,0.f,0.f,0.f}};
#pragma unroll
    for (int ks = 0; ks < 8; ++ks) {
        f16x8 A = *(const f16x8u*)(ebase + (2 * ks + khb) * 256);
#pragma unroll
        for (int nt = 0; nt < 4; ++nt) {
            f16x8 B = *(const f16x8*)(BS + ((ks * 4 + nt) * 64 + lane) * 8);
            acc[nt] = __builtin_amdgcn_mfma_f32_16x16x32_f16(A, B, acc[nt], 0, 0, 0);
        }
    }

    // D: col = lane&15 = c offset; row = (lane>>4)*4+reg = j offset
    int j0 = jt * 16 + (lane >> 4) * 4;           // <= 60; j0+3 may reach 63
    bool full = (j0 <= 56);
#pragma unroll
    for (int nt = 0; nt < 4; ++nt) {
        int cc = nt * 16 + (lane & 15);
        size_t sbase = (size_t)(b * 64 + cc) * PLANE + (size_t)i * 61 + j0;
        if (MODE == 0) {
            f32x4 u4;
            f16x8 mv8;
#pragma unroll
            for (int rg = 0; rg < 4; ++rg) {
                float g  = acc[nt][rg];
                float m2 = (1.f - B1F) * g;
                float v2 = (1.f - B2F) * g * g;
                u4[rg] = LRF * (m2 * rbc1) / (sqrtf(v2 * rbc2) + EPSF);
                mv8[2 * rg]     = (f16)m2;
                mv8[2 * rg + 1] = (f16)v2;
            }
            if (full) {
                *(f32x4u*)(u + sbase) = u4;
                *(f16x8a*)(mv + 2 * sbase) = mv8;
            } else {
                u[sbase] = u4[0];
                mv[2 * sbase] = mv8[0];
                mv[2 * sbase + 1] = mv8[1];
            }
            f16* ab = actc + ((size_t)(b * 62 + i) * 68 + (j0 + 4)) * 64 + cc;
#pragma unroll
            for (int rg = 0; rg < 4; ++rg)
                if (j0 + rg <= 60) ab[rg * 64] = (f16)fmaxf(u4[rg] - LAMF, 0.f);
        } else {
            f32x4 uu;
            f16x8 mv8;
            if (full) {
                uu  = *(const f32x4u*)(u + sbase);
                mv8 = *(const f16x8a*)(mv + 2 * sbase);
            } else {
                uu[0] = u[sbase]; uu[1] = uu[2] = uu[3] = 0.f;
                mv8[0] = mv[2 * sbase]; mv8[1] = mv[2 * sbase + 1];
            }
            float un[4];
#pragma unroll
            for (int rg = 0; rg < 4; ++rg) {
                float a  = fmaxf(uu[rg] - LAMF, 0.f);
                float g  = acc[nt][rg] + a - uu[rg];
                float m2 = B1F * (float)mv8[2 * rg]     + (1.f - B1F) * g;
                float v2 = B2F * (float)mv8[2 * rg + 1] + (1.f - B2F) * g * g;
                mv8[2 * rg]     = (f16)m2;
                mv8[2 * rg + 1] = (f16)v2;
                un[rg] = uu[rg] + LRF * (m2 * rbc1) / (sqrtf(v2 * rbc2) + EPSF);
            }
            if (MODE == 1) {
                if (full) {
                    f32x4 u4 = {un[0], un[1], un[2], un[3]};
                    *(f32x4u*)(u + sbase) = u4;
                    *(f16x8a*)(mv + 2 * sbase) = mv8;
                } else {
                    u[sbase] = un[0];
                    mv[2 * sbase] = mv8[0];
                    mv[2 * sbase + 1] = mv8[1];
                }
                f16* ab = actc + ((size_t)(b * 62 + i) * 68 + (j0 + 4)) * 64 + cc;
#pragma unroll
                for (int rg = 0; rg < 4; ++rg)
                    if (j0 + rg <= 60) ab[rg * 64] = (f16)fmaxf(un[rg] - LAMF, 0.f);
            } else {                              // MODE 2: output only
                float* ob = out + (((size_t)b * 61 + i) * 61 + j0) * 64 + cc;
#pragma unroll
                for (int rg = 0; rg < 4; ++rg)
                    if (j0 + rg <= 60) ob[rg * 64] = fmaxf(un[rg] - LAMF, 0.f);
            }
        }
    }
}

// ---------------------------------------------------------------------------
extern "C" void kernel_launch(void* const* d_in, const int* in_sizes, int n_in,
                              void* d_out, int out_size, void* d_ws, size_t ws_size,
                              hipStream_t stream) {
    const float* img  = (const float*)d_in[0];
    const float* filt = (const float*)d_in[1];
    float* out = (float*)d_out;

    float* u  = (float*)d_ws;
    f16* mv   = (f16*)(u + USZ);      // 2*USZ f16 interleaved (m,v)
    f16* eh   = mv + 2 * (size_t)USZ; // eh before actc: gk tail OOB reads land in actc
    f16* actc = eh + ESZ;
    f16* F2f  = actc + ACSZ;
    f16* Bf   = F2f + 16384;

    hipMemsetAsync(actc, 0, (size_t)ACSZ * sizeof(f16), stream);
    prep<<<128, 256, 0, stream>>>(filt, F2f, Bf);
    cvt<<<ESZ / 1024, 256, 0, stream>>>(img, eh);

    float b1p = B1F, b2p = B2F;
    gk<0><<<1952, 256, 0, stream>>>(u, mv, actc, out, eh, Bf,
                                    1.f / (1.f - b1p), 1.f / (1.f - b2p));
    for (int t = 1; t < 9; ++t) {
        b1p *= B1F;
        b2p *= B2F;
        ek<<<1024, 256, 0, stream>>>(actc, img, F2f, eh);
        gk<1><<<1952, 256, 0, stream>>>(u, mv, actc, out, eh, Bf,
                                        1.f / (1.f - b1p), 1.f / (1.f - b2p));
    }
    b1p *= B1F;
    b2p *= B2F;
    ek<<<1024, 256, 0, stream>>>(actc, img, F2f, eh);
    gk<2><<<1952, 256, 0, stream>>>(u, mv, actc, out, eh, Bf,
                                    1.f / (1.f - b1p), 1.f / (1.f - b2p));
}